// Round 6
// baseline (2950.735 us; speedup 1.0000x reference)
//
#include <hip/hip_runtime.h>
#include <hip/hip_bf16.h>
#include <stdint.h>

// ---------------------------------------------------------------------------
// BiLSTM-CRF on MI355X.  B=128, T=256, E=256, H2=256, NTAGS=76.
//   build_a3   : embedding gather + split-bf16 (hi,hi,lo) A [32768 x 768]
//   build_b3t  : Wih both dirs split-bf16 (hi,lo,hi) B^T    [2048 x 768]
//   gemm_chunk : bf16 MFMA GEMM (3-term compensated == fp32-class) computing
//                xproj for a 64-step time chunk (both dirs)
//   lstm_rec   : fp32 recurrence, 64 steps/launch. 16 clusters x 16 WGs.
//                h exchanged as {f32 val, u32 tag} packed 8B LLC stores
//                (sc0 sc1 = chip-coherent, no cache maintenance). Readers
//                SENTINEL-poll one 8B entry, then bulk-load + verify-all:
//                the 16 entries a thread needs are written by one coalesced
//                producer wave, so they arrive together (R4's 128B re-poll
//                sweep congested the LLC fabric -- that was the regression).
//   out_proj   : feats = lstm_out @ W_out^T + b_out (fp32)
//   viterbi    : per-batch decode + backtrack -> score + path
// ---------------------------------------------------------------------------

#define T_      256
#define NT_     76
#define K3_     768
#define START_  74
#define STOP_   75
#define NEGV    (-10000.0f)

// ws offsets (bytes)
#define OFF_A3    ((size_t)0)                         // u16 [32768][768]   48 MiB
#define OFF_B3T   (OFF_A3    + (size_t)50331648)      // u16 [2048][768]     3 MiB
#define OFF_XPROJ (OFF_B3T   + (size_t)3145728)       // f32 [2][128][64][1024] 64 MiB
#define OFF_LSTM  (OFF_XPROJ + (size_t)67108864)      // f32 [32768][512]   64 MiB
#define OFF_HBUF  (OFF_LSTM  + (size_t)67108864)      // u64 [2][16][256][16] 1 MiB
#define OFF_CBUF  (OFF_HBUF  + (size_t)2097152)       // f32 [2][128][256] 256 KiB
#define OFF_FEATS OFF_A3                              // f32 [32768][76] aliases A3

typedef __attribute__((ext_vector_type(8))) short short8;
typedef __attribute__((ext_vector_type(4))) float float4v;
typedef __attribute__((ext_vector_type(4))) unsigned int uint4v;
typedef __attribute__((ext_vector_type(2))) unsigned int uint2v;
typedef const __attribute__((address_space(1))) unsigned int gas_uint;
typedef __attribute__((address_space(3))) unsigned int las_uint;

__device__ __forceinline__ unsigned short f2bf(float x) {
    unsigned int u = __float_as_uint(x);
    u = (u + 0x7fffu + ((u >> 16) & 1u)) >> 16;   // RNE
    return (unsigned short)u;
}
__device__ __forceinline__ float bf2f(unsigned short h) {
    return __uint_as_float(((unsigned int)h) << 16);
}
__device__ __forceinline__ void gl_lds16(const void* g, void* l) {
    __builtin_amdgcn_global_load_lds((gas_uint*)g, (las_uint*)l, 16, 0, 0);
}
// LLC-direct (bypass L1+L2, coherent across XCDs) helpers.
__device__ __forceinline__ uint4v llc_ld4u(const void* p) {
    uint4v r;
    asm volatile("global_load_dwordx4 %0, %1, off sc0 sc1" : "=v"(r) : "v"(p) : "memory");
    return r;
}
__device__ __forceinline__ uint2v llc_ld2u(const void* p) {
    uint2v r;
    asm volatile("global_load_dwordx2 %0, %1, off sc0 sc1" : "=v"(r) : "v"(p) : "memory");
    return r;
}
__device__ __forceinline__ void llc_st2(void* p, uint2v v) {
    asm volatile("global_store_dwordx2 %0, %1, off sc0 sc1" :: "v"(p), "v"(v) : "memory");
}
__device__ __forceinline__ void wait_vm0() { asm volatile("s_waitcnt vmcnt(0)" ::: "memory"); }
__device__ __forceinline__ void bar_lgkm() {
    asm volatile("s_waitcnt lgkmcnt(0)\ns_barrier" ::: "memory");
}

// ---------------------------------------------------------------------------
__global__ __launch_bounds__(256) void build_a3(const int* __restrict__ ids,
                                                const float* __restrict__ emb,
                                                unsigned short* __restrict__ a3) {
    int m = blockIdx.x, k = threadIdx.x;
    int id = ids[m];
    float x = emb[(size_t)id * 256 + k];
    unsigned short hu = f2bf(x);
    unsigned short lu = f2bf(x - bf2f(hu));
    size_t base = (size_t)m * K3_;
    a3[base + k]       = hu;
    a3[base + 256 + k] = hu;
    a3[base + 512 + k] = lu;
}

__global__ __launch_bounds__(256) void build_b3t(const float* __restrict__ wf,
                                                 const float* __restrict__ wb,
                                                 unsigned short* __restrict__ b3t) {
    int n = blockIdx.x, k = threadIdx.x;
    const float* w = (n < 1024) ? wf : wb;
    int j = n & 1023;
    float x = w[(size_t)j * 256 + k];
    unsigned short hu = f2bf(x);
    unsigned short lu = f2bf(x - bf2f(hu));
    size_t base = (size_t)n * K3_;
    b3t[base + k]       = hu;
    b3t[base + 256 + k] = lu;
    b3t[base + 512 + k] = hu;
}

// ---------------------------------------------------------------------------
// xproj chunk GEMM.  grid = 2 dirs x 64 m-tiles x 8 n-tiles = 1024 blocks.
// ---------------------------------------------------------------------------
__global__ __launch_bounds__(256) void gemm_chunk(const unsigned short* __restrict__ A,
                                                  const unsigned short* __restrict__ Bt,
                                                  float* __restrict__ C, int t0) {
    __shared__ __align__(16) unsigned short As[128 * 64];
    __shared__ __align__(16) unsigned short Bs[128 * 64];
    int tid = threadIdx.x, bx = blockIdx.x;
    int d = bx >> 9, rem = bx & 511;
    int tm = rem >> 3, tn = rem & 7;
    int m0 = tm * 128, n0l = tn * 128;
    int tbase = d ? (192 - t0) : t0;
    int lane = tid & 63, wave = tid >> 6;
    int wm = (wave & 1) * 64, wn = (wave >> 1) * 64;
    int quad = lane >> 4, r16 = lane & 15;

    float4v acc[4][4];
#pragma unroll
    for (int i = 0; i < 4; i++)
#pragma unroll
        for (int j = 0; j < 4; j++) acc[i][j] = (float4v){0.f, 0.f, 0.f, 0.f};

    for (int kt = 0; kt < 12; ++kt) {
        int k0 = kt * 64;
#pragma unroll
        for (int i = 0; i < 4; ++i) {
            int c = i * 256 + tid;
            int row = c >> 3, col = c & 7;
            int rowm = m0 + row;
            int arow = (rowm >> 6) * 256 + tbase + (rowm & 63);
            int brow = d * 1024 + n0l + row;
            gl_lds16(A  + (size_t)arow * K3_ + k0 + col * 8, (unsigned short*)As + (size_t)c * 8);
            gl_lds16(Bt + (size_t)brow * K3_ + k0 + col * 8, (unsigned short*)Bs + (size_t)c * 8);
        }
        __syncthreads();
#pragma unroll
        for (int kk = 0; kk < 64; kk += 32) {
            short8 a[4], b[4];
#pragma unroll
            for (int i = 0; i < 4; i++) {
                a[i] = *(const short8*)&As[(wm + i * 16 + r16) * 64 + kk + quad * 8];
                b[i] = *(const short8*)&Bs[(wn + i * 16 + r16) * 64 + kk + quad * 8];
            }
#pragma unroll
            for (int i = 0; i < 4; i++)
#pragma unroll
                for (int j = 0; j < 4; j++)
                    acc[i][j] = __builtin_amdgcn_mfma_f32_16x16x32_bf16(a[i], b[j], acc[i][j], 0, 0, 0);
        }
        __syncthreads();
    }
#pragma unroll
    for (int i = 0; i < 4; i++)
#pragma unroll
        for (int j = 0; j < 4; j++)
#pragma unroll
            for (int r = 0; r < 4; r++) {
                int ml = wm + i * 16 + quad * 4 + r;
                int rowm = m0 + ml;
                int b = rowm >> 6, tl = rowm & 63;
                int n = n0l + wn + j * 16 + r16;
                C[(((size_t)(d * 128 + b)) * 64 + tl) * 1024 + n] = acc[i][j][r];
            }
}

// ---------------------------------------------------------------------------
// Recurrence, 64 steps per launch.  256 WGs x 256 thr, 16 clusters x 16 WGs.
// hbuf: u64 [parity][cluster][unit 0..255][sample 0..15] = {f32 h, u32 tag}.
// Reader thread tid needs [unit=tid][samples 0..15]: all 16 entries are the
// coalesced store of ONE producer wave -> sentinel-poll entry 0 (8B), then
// bulk-load 128B + verify all tags (split-line straggle -> rare bulk retry).
// ---------------------------------------------------------------------------
#define HSTR 20

__global__ __launch_bounds__(256) void lstm_rec(
    const float* __restrict__ xproj,
    const float* __restrict__ whh_f, const float* __restrict__ whh_b,
    const float* __restrict__ bih_f, const float* __restrict__ bhh_f,
    const float* __restrict__ bih_b, const float* __restrict__ bhh_b,
    const float* __restrict__ h0,    const float* __restrict__ c0,
    float* __restrict__ lstm_out, unsigned long long* hb, float* cbuf, int t0) {

    int bx = blockIdx.x;
    int xcd = bx & 7, m8 = bx >> 3;
    int cid = xcd * 2 + (m8 >> 4);           // cluster id [0,16)
    int s   = m8 & 15;                       // hidden-slice [0,16)
    int d   = cid & 1, g = cid >> 1;
    int tid = threadIdx.x;

    // phase-B identity: wave q = k-quarter, lane r = gate*16 + ulocal
    int q = tid >> 6, r = tid & 63;
    int rowB = (r >> 4) * 256 + s * 16 + (r & 15);
    const float* whh = d ? whh_b : whh_f;
    float4 w4[16];
    {
        const float4* wp = (const float4*)(whh + (size_t)rowB * 256 + q * 64);
#pragma unroll
        for (int i = 0; i < 16; i++) w4[i] = wp[i];
    }

    // phase-C identity: unit-major for coalesced publish
    int u2 = tid >> 4, b2 = tid & 15;
    int ug2 = s * 16 + u2;
    int bg2 = g * 16 + b2;
    const float* bih = d ? bih_b : bih_f;
    const float* bhh = d ? bhh_b : bhh_f;
    float bias[4];
#pragma unroll
    for (int gg = 0; gg < 4; gg++) bias[gg] = bih[gg * 256 + ug2] + bhh[gg * 256 + ug2];
    size_t cidx = ((size_t)d * 128 + bg2) * 256 + ug2;
    float cst = (t0 == 0) ? c0[cidx] : cbuf[cidx];

    __shared__ __align__(16) float h_lds[256 * HSTR];
    __shared__ __align__(16) float red[256 * HSTR];

    const size_t HB_PAR = (size_t)16 * 4096;               // u64 entries per parity
    const unsigned long long* hb_rd = hb + (size_t)cid * 4096 + (size_t)tid * 16;
    unsigned long long* hb_wr = hb + (size_t)cid * 4096 + (size_t)ug2 * 16 + b2;

    for (int tl = 0; tl < 64; ++tl) {
        int t = t0 + tl;
        int tloc = d ? (63 - tl) : tl;

        // xproj prefetch (latency hidden under the poll's waitcnt)
        float xp[4];
        {
            const float* xb = xproj + (((size_t)(d * 128 + bg2)) * 64 + tloc) * 1024 + ug2;
#pragma unroll
            for (int gg = 0; gg < 4; gg++) xp[gg] = xb[gg * 256];
        }

        // ---- P1: obtain h_t (16 samples of unit tid) and stage into LDS
        float4 f[4];
        if (t == 0) {
#pragma unroll
            for (int i = 0; i < 4; i++)
#pragma unroll
                for (int j = 0; j < 4; j++)
                    ((float*)&f[i])[j] = h0[((size_t)d * 128 + g * 16 + (i * 4 + j)) * 256 + tid];
        } else {
            const unsigned long long* src = hb_rd + (size_t)(t & 1) * HB_PAR;
            unsigned tag = (unsigned)t;
            // sentinel: 8B poll until the producer wave's store has landed
            for (;;) {
                uint2v s0 = llc_ld2u(src);
                wait_vm0();
                if (s0.y == tag) break;
                __builtin_amdgcn_s_sleep(1);
            }
            // bulk: 128B load + verify-all (rare retry on split-line straggle)
            uint4v qq[8];
            for (;;) {
#pragma unroll
                for (int i = 0; i < 8; i++) qq[i] = llc_ld4u(src + i * 2);
                wait_vm0();
                bool ok = true;
#pragma unroll
                for (int i = 0; i < 8; i++) ok &= (qq[i].y == tag) & (qq[i].w == tag);
                if (ok) break;
                __builtin_amdgcn_s_sleep(1);
            }
            // coalesced lstm_out store for the PREVIOUS step (h_t = out[t-1])
            if (tl > 0) {
                int tsp = d ? (255 - (t - 1)) : (t - 1);
#pragma unroll
                for (int b = 0; b < 16; b++) {
                    unsigned uv = (b & 1) ? qq[b >> 1].z : qq[b >> 1].x;
                    lstm_out[((size_t)(g * 16 + b) * 256 + tsp) * 512 + d * 256 + tid] =
                        __uint_as_float(uv);
                }
            }
#pragma unroll
            for (int i = 0; i < 4; i++)
                f[i] = make_float4(__uint_as_float(qq[2 * i].x), __uint_as_float(qq[2 * i].z),
                                   __uint_as_float(qq[2 * i + 1].x), __uint_as_float(qq[2 * i + 1].z));
        }
        {
            float4* dst = (float4*)&h_lds[tid * HSTR];
            dst[0] = f[0]; dst[1] = f[1]; dst[2] = f[2]; dst[3] = f[3];
        }
        bar_lgkm();                            // B1 (lgkm only -- no vm drain)

        // ---- P2: partial gates acc[b] = sum_{k in quarter} w[k]*h[k][b]
        float acc[16];
#pragma unroll
        for (int b = 0; b < 16; b++) acc[b] = 0.f;
        const float* hq = h_lds + q * 64 * HSTR;
#pragma unroll
        for (int k4 = 0; k4 < 16; ++k4) {
            float4 wv = w4[k4];
#pragma unroll
            for (int kk = 0; kk < 4; ++kk) {
                float wx = (kk == 0) ? wv.x : (kk == 1) ? wv.y : (kk == 2) ? wv.z : wv.w;
                const float4* hv = (const float4*)(hq + (k4 * 4 + kk) * HSTR);
                float4 ha = hv[0], hb4 = hv[1], hc = hv[2], hd = hv[3];   // broadcast
                acc[0]  += wx * ha.x;  acc[1]  += wx * ha.y;  acc[2]  += wx * ha.z;  acc[3]  += wx * ha.w;
                acc[4]  += wx * hb4.x; acc[5]  += wx * hb4.y; acc[6]  += wx * hb4.z; acc[7]  += wx * hb4.w;
                acc[8]  += wx * hc.x;  acc[9]  += wx * hc.y;  acc[10] += wx * hc.z;  acc[11] += wx * hc.w;
                acc[12] += wx * hd.x;  acc[13] += wx * hd.y;  acc[14] += wx * hd.z;  acc[15] += wx * hd.w;
            }
        }
        {
            float4* rp = (float4*)&red[(q * 64 + r) * HSTR];
            rp[0] = make_float4(acc[0], acc[1], acc[2], acc[3]);
            rp[1] = make_float4(acc[4], acc[5], acc[6], acc[7]);
            rp[2] = make_float4(acc[8], acc[9], acc[10], acc[11]);
            rp[3] = make_float4(acc[12], acc[13], acc[14], acc[15]);
        }
        bar_lgkm();                            // B2

        // ---- P3: combine, cell update, publish {h, tag} (fire-and-forget)
        float gate[4];
#pragma unroll
        for (int gg = 0; gg < 4; gg++) {
            int rr = gg * 16 + u2;
            gate[gg] = red[(0 * 64 + rr) * HSTR + b2] + red[(1 * 64 + rr) * HSTR + b2] +
                       red[(2 * 64 + rr) * HSTR + b2] + red[(3 * 64 + rr) * HSTR + b2] +
                       xp[gg] + bias[gg];
        }
        float iv = 1.f / (1.f + expf(-gate[0]));
        float fv = 1.f / (1.f + expf(-gate[1]));
        float gv = tanhf(gate[2]);
        float ov = 1.f / (1.f + expf(-gate[3]));
        cst = fv * cst + iv * gv;
        float hv = ov * tanhf(cst);

        uint2v pk;
        pk.x = __float_as_uint(hv);
        pk.y = (unsigned)(t + 1);
        llc_st2(hb_wr + (size_t)((t + 1) & 1) * HB_PAR, pk);
    }

    // ---- epilogue: poll final h of this chunk, store last lstm_out slice
    {
        int te = t0 + 64;
        const unsigned long long* src = hb_rd + (size_t)(te & 1) * HB_PAR;
        unsigned tag = (unsigned)te;
        for (;;) {
            uint2v s0 = llc_ld2u(src);
            wait_vm0();
            if (s0.y == tag) break;
            __builtin_amdgcn_s_sleep(1);
        }
        uint4v qq[8];
        for (;;) {
#pragma unroll
            for (int i = 0; i < 8; i++) qq[i] = llc_ld4u(src + i * 2);
            wait_vm0();
            bool ok = true;
#pragma unroll
            for (int i = 0; i < 8; i++) ok &= (qq[i].y == tag) & (qq[i].w == tag);
            if (ok) break;
            __builtin_amdgcn_s_sleep(1);
        }
        int tsp = d ? (255 - (te - 1)) : (te - 1);
#pragma unroll
        for (int b = 0; b < 16; b++) {
            unsigned uv = (b & 1) ? qq[b >> 1].z : qq[b >> 1].x;
            lstm_out[((size_t)(g * 16 + b) * 256 + tsp) * 512 + d * 256 + tid] =
                __uint_as_float(uv);
        }
    }
    cbuf[cidx] = cst;
}

// ---------------------------------------------------------------------------
__global__ __launch_bounds__(256) void out_proj(const float* __restrict__ lstm,
                                                const float* __restrict__ wout,
                                                const float* __restrict__ bout,
                                                float* __restrict__ feats) {
    __shared__ __align__(16) float hrow[16 * 512];
    int tid = threadIdx.x;
    size_t m0 = (size_t)blockIdx.x * 16;
    {
        const float4* src = (const float4*)(lstm + m0 * 512);
        float4* dst = (float4*)hrow;
        for (int i = tid; i < 2048; i += 256) dst[i] = src[i];
    }
    __syncthreads();
    int n = tid & 127, rh = tid >> 7;
    int nn = (n < NT_) ? n : 0;
    float acc[8];
#pragma unroll
    for (int rr = 0; rr < 8; rr++) acc[rr] = 0.f;
    const float* wrow = wout + (size_t)nn * 512;
    for (int k = 0; k < 512; k += 4) {
        float4 wv = *(const float4*)&wrow[k];
#pragma unroll
        for (int rr = 0; rr < 8; ++rr) {
            float4 hv = *(const float4*)&hrow[(rh * 8 + rr) * 512 + k];
            acc[rr] += wv.x * hv.x + wv.y * hv.y + wv.z * hv.z + wv.w * hv.w;
        }
    }
    if (n < NT_) {
        float bb = bout[n];
#pragma unroll
        for (int rr = 0; rr < 8; ++rr)
            feats[(m0 + rh * 8 + rr) * NT_ + n] = acc[rr] + bb;
    }
}

// ---------------------------------------------------------------------------
__global__ __launch_bounds__(128) void viterbi(const float* __restrict__ feats,
                                               const float* __restrict__ trans,
                                               float* __restrict__ out) {
    int b = blockIdx.x, tid = threadIdx.x;
    __shared__ float fvbuf[2][80];
    __shared__ float termbuf[80];
    __shared__ unsigned char bptr[256][NT_];

    float trr[NT_];
    if (tid < NT_) {
#pragma unroll
        for (int p = 0; p < NT_; p++) trr[p] = trans[tid * NT_ + p];
    }
    if (tid < 80) fvbuf[0][tid] = (tid == START_) ? 0.f : NEGV;
    __syncthreads();

    const float* fb = feats + (size_t)b * T_ * NT_;
    for (int t = 0; t < T_; ++t) {
        int par = t & 1;
        if (tid < NT_) {
            float feat = fb[t * NT_ + tid];
            const float* fv = fvbuf[par];
            float best = fv[0] + trr[0];
            int arg = 0;
#pragma unroll
            for (int p = 1; p < NT_; ++p) {
                float sc = fv[p] + trr[p];
                if (sc > best) { best = sc; arg = p; }
            }
            bptr[t][tid] = (unsigned char)arg;
            fvbuf[1 - par][tid] = best + feat;
        }
        __syncthreads();
    }
    if (tid < NT_) termbuf[tid] = fvbuf[0][tid] + trans[STOP_ * NT_ + tid];
    __syncthreads();
    if (tid == 0) {
        float best = termbuf[0];
        int arg = 0;
        for (int p = 1; p < NT_; ++p)
            if (termbuf[p] > best) { best = termbuf[p]; arg = p; }
        out[b] = best;
        int tag = arg;
        float* pout = out + 128 + (size_t)b * T_;
        for (int t = T_ - 1; t >= 0; --t) {
            pout[t] = (float)tag;
            tag = bptr[t][tag];
        }
    }
}

// ---------------------------------------------------------------------------
extern "C" void kernel_launch(void* const* d_in, const int* in_sizes, int n_in,
                              void* d_out, int out_size, void* d_ws, size_t ws_size,
                              hipStream_t stream) {
    const int*   ids   = (const int*)  d_in[0];
    const float* emb   = (const float*)d_in[1];
    const float* wih_f = (const float*)d_in[2];
    const float* whh_f = (const float*)d_in[3];
    const float* bih_f = (const float*)d_in[4];
    const float* bhh_f = (const float*)d_in[5];
    const float* wih_b = (const float*)d_in[6];
    const float* whh_b = (const float*)d_in[7];
    const float* bih_b = (const float*)d_in[8];
    const float* bhh_b = (const float*)d_in[9];
    const float* h0    = (const float*)d_in[10];
    const float* c0    = (const float*)d_in[11];
    const float* wout  = (const float*)d_in[12];
    const float* bout  = (const float*)d_in[13];
    const float* trans = (const float*)d_in[14];

    char* ws = (char*)d_ws;
    unsigned short* A3  = (unsigned short*)(ws + OFF_A3);
    unsigned short* B3T = (unsigned short*)(ws + OFF_B3T);
    float* XPROJ        = (float*)(ws + OFF_XPROJ);
    float* LSTM         = (float*)(ws + OFF_LSTM);
    unsigned long long* HBUF = (unsigned long long*)(ws + OFF_HBUF);
    float* CBUF         = (float*)(ws + OFF_CBUF);
    float* FEATS        = (float*)(ws + OFF_FEATS);   // aliases A3 (dead by then)

    build_a3 <<<32768, 256, 0, stream>>>(ids, emb, A3);
    build_b3t<<<2048,  256, 0, stream>>>(wih_f, wih_b, B3T);
    for (int c = 0; c < 4; ++c) {
        gemm_chunk<<<1024, 256, 0, stream>>>(A3, B3T, XPROJ, c * 64);
        lstm_rec  <<<256,  256, 0, stream>>>(XPROJ, whh_f, whh_b, bih_f, bhh_f, bih_b, bhh_b,
                                             h0, c0, LSTM, HBUF, CBUF, c * 64);
    }
    out_proj<<<2048, 256, 0, stream>>>(LSTM, wout, bout, FEATS);
    viterbi <<<128,  128, 0, stream>>>(FEATS, trans, (float*)d_out);
}

// Round 8
// 1924.059 us; speedup vs baseline: 1.5336x; 1.5336x over previous
//
#include <hip/hip_runtime.h>
#include <hip/hip_bf16.h>
#include <stdint.h>

// ---------------------------------------------------------------------------
// BiLSTM-CRF on MI355X.  B=128, T=256, E=256, H2=256, NTAGS=76.
//   build_a3   : embedding gather + split-bf16 (hi,hi,lo) A [32768 x 768]
//   build_b3t  : Wih both dirs split-bf16 (hi,lo,hi) B^T    [2048 x 768]
//   gemm_chunk : bf16 MFMA GEMM (3-term compensated == fp32-class) computing
//                xproj for a 64-step time chunk (both dirs)
//   lstm_rec   : fp32 recurrence, 64 steps/launch. 16 clusters x 16 WGs.
//                h exchanged as fused {f32 val, u32 tag} 8B LLC stores
//                (sc0 sc1), fire-and-forget; every thread polls exactly the
//                data it needs with verify-all-tags retry (R4 structure,
//                proven). NEW vs R4: bulk mapping is wave-coalesced --
//                instr k loads 16B at entry k*512+tid*2 (16 lines/instr vs
//                R4's 64) => 4x less LLC line traffic per retry round.
//   out_proj   : feats = lstm_out @ W_out^T + b_out (fp32)
//   viterbi    : per-batch decode + backtrack -> score + path
// ---------------------------------------------------------------------------

#define T_      256
#define NT_     76
#define K3_     768
#define START_  74
#define STOP_   75
#define NEGV    (-10000.0f)

// ws offsets (bytes)
#define OFF_A3    ((size_t)0)                         // u16 [32768][768]   48 MiB
#define OFF_B3T   (OFF_A3    + (size_t)50331648)      // u16 [2048][768]     3 MiB
#define OFF_XPROJ (OFF_B3T   + (size_t)3145728)       // f32 [2][128][64][1024] 64 MiB
#define OFF_LSTM  (OFF_XPROJ + (size_t)67108864)      // f32 [32768][512]   64 MiB
#define OFF_HBUF  (OFF_LSTM  + (size_t)67108864)      // u64 [2][16][256][16] 1 MiB
#define OFF_CBUF  (OFF_HBUF  + (size_t)2097152)       // f32 [2][128][256] 256 KiB
#define OFF_FEATS OFF_A3                              // f32 [32768][76] aliases A3

typedef __attribute__((ext_vector_type(8))) short short8;
typedef __attribute__((ext_vector_type(4))) float float4v;
typedef __attribute__((ext_vector_type(4))) unsigned int uint4v;
typedef __attribute__((ext_vector_type(2))) unsigned int uint2v;
typedef const __attribute__((address_space(1))) unsigned int gas_uint;
typedef __attribute__((address_space(3))) unsigned int las_uint;

__device__ __forceinline__ unsigned short f2bf(float x) {
    unsigned int u = __float_as_uint(x);
    u = (u + 0x7fffu + ((u >> 16) & 1u)) >> 16;   // RNE
    return (unsigned short)u;
}
__device__ __forceinline__ float bf2f(unsigned short h) {
    return __uint_as_float(((unsigned int)h) << 16);
}
__device__ __forceinline__ void gl_lds16(const void* g, void* l) {
    __builtin_amdgcn_global_load_lds((gas_uint*)g, (las_uint*)l, 16, 0, 0);
}
// LLC-direct (bypass L1+L2, coherent across XCDs) helpers.
__device__ __forceinline__ uint4v llc_ld4u(const void* p) {
    uint4v r;
    asm volatile("global_load_dwordx4 %0, %1, off sc0 sc1" : "=v"(r) : "v"(p) : "memory");
    return r;
}
__device__ __forceinline__ void llc_st2(void* p, uint2v v) {
    asm volatile("global_store_dwordx2 %0, %1, off sc0 sc1" :: "v"(p), "v"(v) : "memory");
}
__device__ __forceinline__ void wait_vm0() { asm volatile("s_waitcnt vmcnt(0)" ::: "memory"); }
__device__ __forceinline__ void bar_lgkm() {
    asm volatile("s_waitcnt lgkmcnt(0)\ns_barrier" ::: "memory");
}

// ---------------------------------------------------------------------------
__global__ __launch_bounds__(256) void build_a3(const int* __restrict__ ids,
                                                const float* __restrict__ emb,
                                                unsigned short* __restrict__ a3) {
    int m = blockIdx.x, k = threadIdx.x;
    int id = ids[m];
    float x = emb[(size_t)id * 256 + k];
    unsigned short hu = f2bf(x);
    unsigned short lu = f2bf(x - bf2f(hu));
    size_t base = (size_t)m * K3_;
    a3[base + k]       = hu;
    a3[base + 256 + k] = hu;
    a3[base + 512 + k] = lu;
}

__global__ __launch_bounds__(256) void build_b3t(const float* __restrict__ wf,
                                                 const float* __restrict__ wb,
                                                 unsigned short* __restrict__ b3t) {
    int n = blockIdx.x, k = threadIdx.x;
    const float* w = (n < 1024) ? wf : wb;
    int j = n & 1023;
    float x = w[(size_t)j * 256 + k];
    unsigned short hu = f2bf(x);
    unsigned short lu = f2bf(x - bf2f(hu));
    size_t base = (size_t)n * K3_;
    b3t[base + k]       = hu;
    b3t[base + 256 + k] = lu;
    b3t[base + 512 + k] = hu;
}

// ---------------------------------------------------------------------------
// xproj chunk GEMM.  grid = 2 dirs x 64 m-tiles x 8 n-tiles = 1024 blocks.
// ---------------------------------------------------------------------------
__global__ __launch_bounds__(256) void gemm_chunk(const unsigned short* __restrict__ A,
                                                  const unsigned short* __restrict__ Bt,
                                                  float* __restrict__ C, int t0) {
    __shared__ __align__(16) unsigned short As[128 * 64];
    __shared__ __align__(16) unsigned short Bs[128 * 64];
    int tid = threadIdx.x, bx = blockIdx.x;
    int d = bx >> 9, rem = bx & 511;
    int tm = rem >> 3, tn = rem & 7;
    int m0 = tm * 128, n0l = tn * 128;
    int tbase = d ? (192 - t0) : t0;
    int lane = tid & 63, wave = tid >> 6;
    int wm = (wave & 1) * 64, wn = (wave >> 1) * 64;
    int quad = lane >> 4, r16 = lane & 15;

    float4v acc[4][4];
#pragma unroll
    for (int i = 0; i < 4; i++)
#pragma unroll
        for (int j = 0; j < 4; j++) acc[i][j] = (float4v){0.f, 0.f, 0.f, 0.f};

    for (int kt = 0; kt < 12; ++kt) {
        int k0 = kt * 64;
#pragma unroll
        for (int i = 0; i < 4; ++i) {
            int c = i * 256 + tid;
            int row = c >> 3, col = c & 7;
            int rowm = m0 + row;
            int arow = (rowm >> 6) * 256 + tbase + (rowm & 63);
            int brow = d * 1024 + n0l + row;
            gl_lds16(A  + (size_t)arow * K3_ + k0 + col * 8, (unsigned short*)As + (size_t)c * 8);
            gl_lds16(Bt + (size_t)brow * K3_ + k0 + col * 8, (unsigned short*)Bs + (size_t)c * 8);
        }
        __syncthreads();
#pragma unroll
        for (int kk = 0; kk < 64; kk += 32) {
            short8 a[4], b[4];
#pragma unroll
            for (int i = 0; i < 4; i++) {
                a[i] = *(const short8*)&As[(wm + i * 16 + r16) * 64 + kk + quad * 8];
                b[i] = *(const short8*)&Bs[(wn + i * 16 + r16) * 64 + kk + quad * 8];
            }
#pragma unroll
            for (int i = 0; i < 4; i++)
#pragma unroll
                for (int j = 0; j < 4; j++)
                    acc[i][j] = __builtin_amdgcn_mfma_f32_16x16x32_bf16(a[i], b[j], acc[i][j], 0, 0, 0);
        }
        __syncthreads();
    }
#pragma unroll
    for (int i = 0; i < 4; i++)
#pragma unroll
        for (int j = 0; j < 4; j++)
#pragma unroll
            for (int r = 0; r < 4; r++) {
                int ml = wm + i * 16 + quad * 4 + r;
                int rowm = m0 + ml;
                int b = rowm >> 6, tl = rowm & 63;
                int n = n0l + wn + j * 16 + r16;
                C[(((size_t)(d * 128 + b)) * 64 + tl) * 1024 + n] = acc[i][j][r];
            }
}

// ---------------------------------------------------------------------------
// Recurrence, 64 steps per launch.  256 WGs x 256 thr, 16 clusters x 16 WGs.
// hbuf: u64 [parity][cluster][unit 0..255][sample 0..15] = {f32 h, u32 tag}.
// Producer WG s writes entry s*256+tid (wave-coalesced 512B/instr).
// Reader (all threads, symmetric -- R4 structure): instr k loads 16B at
// entry k*512 + tid*2 (1KB contiguous per wave-instr), verify all 16 tags,
// retry w/ sleep.  Thread holds units {k*32 + tid>>3}, samples {(tid&7)*2,+1}.
// ---------------------------------------------------------------------------
#define HSTR 20

__global__ __launch_bounds__(256) void lstm_rec(
    const float* __restrict__ xproj,
    const float* __restrict__ whh_f, const float* __restrict__ whh_b,
    const float* __restrict__ bih_f, const float* __restrict__ bhh_f,
    const float* __restrict__ bih_b, const float* __restrict__ bhh_b,
    const float* __restrict__ h0,    const float* __restrict__ c0,
    float* __restrict__ lstm_out, unsigned long long* hb, float* cbuf, int t0) {

    int bx = blockIdx.x;
    int xcd = bx & 7, m8 = bx >> 3;
    int cid = xcd * 2 + (m8 >> 4);           // cluster id [0,16)
    int s   = m8 & 15;                       // hidden-slice [0,16)
    int d   = cid & 1, g = cid >> 1;
    int tid = threadIdx.x;

    // phase-B identity: wave q = k-quarter, lane r = gate*16 + ulocal
    int q = tid >> 6, r = tid & 63;
    int rowB = (r >> 4) * 256 + s * 16 + (r & 15);
    const float* whh = d ? whh_b : whh_f;
    float4 w4[16];
    {
        const float4* wp = (const float4*)(whh + (size_t)rowB * 256 + q * 64);
#pragma unroll
        for (int i = 0; i < 16; i++) w4[i] = wp[i];
    }

    // phase-C identity: unit-major for coalesced publish
    int u2 = tid >> 4, b2 = tid & 15;
    int ug2 = s * 16 + u2;
    int bg2 = g * 16 + b2;
    const float* bih = d ? bih_b : bih_f;
    const float* bhh = d ? bhh_b : bhh_f;
    float bias[4];
#pragma unroll
    for (int gg = 0; gg < 4; gg++) bias[gg] = bih[gg * 256 + ug2] + bhh[gg * 256 + ug2];
    size_t cidx = ((size_t)d * 128 + bg2) * 256 + ug2;
    float cst = (t0 == 0) ? c0[cidx] : cbuf[cidx];

    __shared__ __align__(16) float h_lds[256 * HSTR];
    __shared__ __align__(16) float red[256 * HSTR];

    const size_t HB_PAR = (size_t)16 * 4096;               // u64 entries per parity
    unsigned long long* hbc = hb + (size_t)cid * 4096;
    unsigned long long* hb_wr = hbc + (size_t)s * 256 + tid;   // == ug2*16+b2

    int smp0 = (tid & 7) * 2;                // bulk-mapping: sample pair base
    int urow = tid >> 3;                     // bulk-mapping: unit sub-row

    for (int tl = 0; tl < 64; ++tl) {
        int t = t0 + tl;
        int tloc = d ? (63 - tl) : tl;

        // xproj prefetch (in flight across the poll)
        float xp[4];
        {
            const float* xb = xproj + (((size_t)(d * 128 + bg2)) * 64 + tloc) * 1024 + ug2;
#pragma unroll
            for (int gg = 0; gg < 4; gg++) xp[gg] = xb[gg * 256];
        }

        // ---- P1: obtain h_t and stage into LDS [unit][sample]
        if (t == 0) {
#pragma unroll
            for (int k = 0; k < 8; k++) {
                int uk = k * 32 + urow;
                float v0 = h0[((size_t)d * 128 + g * 16 + smp0)     * 256 + uk];
                float v1 = h0[((size_t)d * 128 + g * 16 + smp0 + 1) * 256 + uk];
                *(float2*)&h_lds[uk * HSTR + smp0] = make_float2(v0, v1);
            }
        } else {
            const unsigned long long* rd = hbc + (size_t)(t & 1) * HB_PAR;
            unsigned tag = (unsigned)t;
            uint4v qq[8];
            for (;;) {                              // poll == data (R4), coalesced (new)
#pragma unroll
                for (int k = 0; k < 8; k++) qq[k] = llc_ld4u(rd + k * 512 + tid * 2);
                wait_vm0();
                bool ok = true;
#pragma unroll
                for (int k = 0; k < 8; k++) ok &= (qq[k].y == tag) & (qq[k].w == tag);
                if (ok) break;
                __builtin_amdgcn_s_sleep(1);
            }
#pragma unroll
            for (int k = 0; k < 8; k++) {
                int uk = k * 32 + urow;
                *(float2*)&h_lds[uk * HSTR + smp0] =
                    make_float2(__uint_as_float(qq[k].x), __uint_as_float(qq[k].z));
            }
        }
        bar_lgkm();                            // B1: h_lds ready

        // lstm_out for step t-1 (h_t == output of step t-1), coalesced rows
        if (tl > 0) {
            int tsp = d ? (255 - (t - 1)) : (t - 1);
#pragma unroll
            for (int b = 0; b < 16; b++)
                lstm_out[((size_t)(g * 16 + b) * 256 + tsp) * 512 + d * 256 + tid] =
                    h_lds[tid * HSTR + b];
        }

        // ---- P2: partial gates acc[b] = sum_{k in quarter} w[k]*h[k][b]
        float acc[16];
#pragma unroll
        for (int b = 0; b < 16; b++) acc[b] = 0.f;
        const float* hq = h_lds + q * 64 * HSTR;
#pragma unroll
        for (int k4 = 0; k4 < 16; ++k4) {
            float4 wv = w4[k4];
#pragma unroll
            for (int kk = 0; kk < 4; ++kk) {
                float wx = (kk == 0) ? wv.x : (kk == 1) ? wv.y : (kk == 2) ? wv.z : wv.w;
                const float4* hv = (const float4*)(hq + (k4 * 4 + kk) * HSTR);
                float4 ha = hv[0], hb4 = hv[1], hc = hv[2], hd = hv[3];   // broadcast
                acc[0]  += wx * ha.x;  acc[1]  += wx * ha.y;  acc[2]  += wx * ha.z;  acc[3]  += wx * ha.w;
                acc[4]  += wx * hb4.x; acc[5]  += wx * hb4.y; acc[6]  += wx * hb4.z; acc[7]  += wx * hb4.w;
                acc[8]  += wx * hc.x;  acc[9]  += wx * hc.y;  acc[10] += wx * hc.z;  acc[11] += wx * hc.w;
                acc[12] += wx * hd.x;  acc[13] += wx * hd.y;  acc[14] += wx * hd.z;  acc[15] += wx * hd.w;
            }
        }
        {
            float4* rp = (float4*)&red[(q * 64 + r) * HSTR];
            rp[0] = make_float4(acc[0], acc[1], acc[2], acc[3]);
            rp[1] = make_float4(acc[4], acc[5], acc[6], acc[7]);
            rp[2] = make_float4(acc[8], acc[9], acc[10], acc[11]);
            rp[3] = make_float4(acc[12], acc[13], acc[14], acc[15]);
        }
        bar_lgkm();                            // B2

        // ---- P3: combine, cell update, publish fused {h, tag} fire-and-forget
        float gate[4];
#pragma unroll
        for (int gg = 0; gg < 4; gg++) {
            int rr = gg * 16 + u2;
            gate[gg] = red[(0 * 64 + rr) * HSTR + b2] + red[(1 * 64 + rr) * HSTR + b2] +
                       red[(2 * 64 + rr) * HSTR + b2] + red[(3 * 64 + rr) * HSTR + b2] +
                       xp[gg] + bias[gg];
        }
        float iv = 1.f / (1.f + expf(-gate[0]));
        float fv = 1.f / (1.f + expf(-gate[1]));
        float gv = tanhf(gate[2]);
        float ov = 1.f / (1.f + expf(-gate[3]));
        cst = fv * cst + iv * gv;
        float hv = ov * tanhf(cst);

        uint2v pk;
        pk.x = __float_as_uint(hv);
        pk.y = (unsigned)(t + 1);
        llc_st2(hb_wr + (size_t)((t + 1) & 1) * HB_PAR, pk);
    }

    // ---- epilogue: fetch final h (tag t0+64), write last lstm_out slice
    {
        int te = t0 + 64;
        const unsigned long long* rd = hbc + (size_t)(te & 1) * HB_PAR;
        unsigned tag = (unsigned)te;
        uint4v qq[8];
        for (;;) {
#pragma unroll
            for (int k = 0; k < 8; k++) qq[k] = llc_ld4u(rd + k * 512 + tid * 2);
            wait_vm0();
            bool ok = true;
#pragma unroll
            for (int k = 0; k < 8; k++) ok &= (qq[k].y == tag) & (qq[k].w == tag);
            if (ok) break;
            __builtin_amdgcn_s_sleep(1);
        }
#pragma unroll
        for (int k = 0; k < 8; k++) {
            int uk = k * 32 + urow;
            *(float2*)&h_lds[uk * HSTR + smp0] =
                make_float2(__uint_as_float(qq[k].x), __uint_as_float(qq[k].z));
        }
        bar_lgkm();
        int tsp = d ? (255 - (te - 1)) : (te - 1);
#pragma unroll
        for (int b = 0; b < 16; b++)
            lstm_out[((size_t)(g * 16 + b) * 256 + tsp) * 512 + d * 256 + tid] =
                h_lds[tid * HSTR + b];
    }
    cbuf[cidx] = cst;
}

// ---------------------------------------------------------------------------
__global__ __launch_bounds__(256) void out_proj(const float* __restrict__ lstm,
                                                const float* __restrict__ wout,
                                                const float* __restrict__ bout,
                                                float* __restrict__ feats) {
    __shared__ __align__(16) float hrow[16 * 512];
    int tid = threadIdx.x;
    size_t m0 = (size_t)blockIdx.x * 16;
    {
        const float4* src = (const float4*)(lstm + m0 * 512);
        float4* dst = (float4*)hrow;
        for (int i = tid; i < 2048; i += 256) dst[i] = src[i];
    }
    __syncthreads();
    int n = tid & 127, rh = tid >> 7;
    int nn = (n < NT_) ? n : 0;
    float acc[8];
#pragma unroll
    for (int rr = 0; rr < 8; rr++) acc[rr] = 0.f;
    const float* wrow = wout + (size_t)nn * 512;
    for (int k = 0; k < 512; k += 4) {
        float4 wv = *(const float4*)&wrow[k];
#pragma unroll
        for (int rr = 0; rr < 8; ++rr) {
            float4 hv = *(const float4*)&hrow[(rh * 8 + rr) * 512 + k];
            acc[rr] += wv.x * hv.x + wv.y * hv.y + wv.z * hv.z + wv.w * hv.w;
        }
    }
    if (n < NT_) {
        float bb = bout[n];
#pragma unroll
        for (int rr = 0; rr < 8; ++rr)
            feats[(m0 + rh * 8 + rr) * NT_ + n] = acc[rr] + bb;
    }
}

// ---------------------------------------------------------------------------
__global__ __launch_bounds__(128) void viterbi(const float* __restrict__ feats,
                                               const float* __restrict__ trans,
                                               float* __restrict__ out) {
    int b = blockIdx.x, tid = threadIdx.x;
    __shared__ float fvbuf[2][80];
    __shared__ float termbuf[80];
    __shared__ unsigned char bptr[256][NT_];

    float trr[NT_];
    if (tid < NT_) {
#pragma unroll
        for (int p = 0; p < NT_; p++) trr[p] = trans[tid * NT_ + p];
    }
    if (tid < 80) fvbuf[0][tid] = (tid == START_) ? 0.f : NEGV;
    __syncthreads();

    const float* fb = feats + (size_t)b * T_ * NT_;
    for (int t = 0; t < T_; ++t) {
        int par = t & 1;
        if (tid < NT_) {
            float feat = fb[t * NT_ + tid];
            const float* fv = fvbuf[par];
            float best = fv[0] + trr[0];
            int arg = 0;
#pragma unroll
            for (int p = 1; p < NT_; ++p) {
                float sc = fv[p] + trr[p];
                if (sc > best) { best = sc; arg = p; }
            }
            bptr[t][tid] = (unsigned char)arg;
            fvbuf[1 - par][tid] = best + feat;
        }
        __syncthreads();
    }
    if (tid < NT_) termbuf[tid] = fvbuf[0][tid] + trans[STOP_ * NT_ + tid];
    __syncthreads();
    if (tid == 0) {
        float best = termbuf[0];
        int arg = 0;
        for (int p = 1; p < NT_; ++p)
            if (termbuf[p] > best) { best = termbuf[p]; arg = p; }
        out[b] = best;
        int tag = arg;
        float* pout = out + 128 + (size_t)b * T_;
        for (int t = T_ - 1; t >= 0; --t) {
            pout[t] = (float)tag;
            tag = bptr[t][tag];
        }
    }
}

// ---------------------------------------------------------------------------
extern "C" void kernel_launch(void* const* d_in, const int* in_sizes, int n_in,
                              void* d_out, int out_size, void* d_ws, size_t ws_size,
                              hipStream_t stream) {
    const int*   ids   = (const int*)  d_in[0];
    const float* emb   = (const float*)d_in[1];
    const float* wih_f = (const float*)d_in[2];
    const float* whh_f = (const float*)d_in[3];
    const float* bih_f = (const float*)d_in[4];
    const float* bhh_f = (const float*)d_in[5];
    const float* wih_b = (const float*)d_in[6];
    const float* whh_b = (const float*)d_in[7];
    const float* bih_b = (const float*)d_in[8];
    const float* bhh_b = (const float*)d_in[9];
    const float* h0    = (const float*)d_in[10];
    const float* c0    = (const float*)d_in[11];
    const float* wout  = (const float*)d_in[12];
    const float* bout  = (const float*)d_in[13];
    const float* trans = (const float*)d_in[14];

    char* ws = (char*)d_ws;
    unsigned short* A3  = (unsigned short*)(ws + OFF_A3);
    unsigned short* B3T = (unsigned short*)(ws + OFF_B3T);
    float* XPROJ        = (float*)(ws + OFF_XPROJ);
    float* LSTM         = (float*)(ws + OFF_LSTM);
    unsigned long long* HBUF = (unsigned long long*)(ws + OFF_HBUF);
    float* CBUF         = (float*)(ws + OFF_CBUF);
    float* FEATS        = (float*)(ws + OFF_FEATS);   // aliases A3 (dead by then)

    build_a3 <<<32768, 256, 0, stream>>>(ids, emb, A3);
    build_b3t<<<2048,  256, 0, stream>>>(wih_f, wih_b, B3T);
    for (int c = 0; c < 4; ++c) {
        gemm_chunk<<<1024, 256, 0, stream>>>(A3, B3T, XPROJ, c * 64);
        lstm_rec  <<<256,  256, 0, stream>>>(XPROJ, whh_f, whh_b, bih_f, bhh_f, bih_b, bhh_b,
                                             h0, c0, LSTM, HBUF, CBUF, c * 64);
    }
    out_proj<<<2048, 256, 0, stream>>>(LSTM, wout, bout, FEATS);
    viterbi <<<128,  128, 0, stream>>>(FEATS, trans, (float*)d_out);
}